// Round 7
// baseline (137.270 us; speedup 1.0000x reference)
//
#include <hip/hip_runtime.h>
#include <math.h>

#define H 512
#define W 512
#define BAND 2
#define NQ 11   // 0:s0(mask) 1-4:s1i..s4i 5-8:s1o..s4o 9:tex 10:shape

__device__ __forceinline__ float2 shfl_up1_f2(float2 v, int lane) {
    float2 r;
    r.x = __shfl_up(v.x, 1);
    r.y = __shfl_up(v.y, 1);
    if (lane == 0) { r.x = 0.0f; r.y = 0.0f; }
    return r;
}
__device__ __forceinline__ float2 shfl_dn1_f2(float2 v, int lane) {
    float2 r;
    r.x = __shfl_down(v.x, 1);
    r.y = __shfl_down(v.y, 1);
    if (lane == 63) { r.x = 0.0f; r.y = 0.0f; }
    return r;
}

__device__ __forceinline__ float2 pk_add(float2 a, float2 b) { return make_float2(a.x + b.x, a.y + b.y); }
__device__ __forceinline__ float2 pk_sub(float2 a, float2 b) { return make_float2(a.x - b.x, a.y - b.y); }
__device__ __forceinline__ float2 pk_mul(float2 a, float2 b) { return make_float2(a.x * b.x, a.y * b.y); }
__device__ __forceinline__ float2 pk_muls(float2 a, float s) { return make_float2(a.x * s, a.y * s); }
__device__ __forceinline__ float2 pk_fma(float2 a, float2 b, float2 c) {
    return make_float2(fmaf(a.x, b.x, c.x), fmaf(a.y, b.y, c.y));
}

// load one row of BOTH images, interleaved: dst[j] = (inp[y][x0+j], outp[y][x0+j])
__device__ __forceinline__ void load_row_pk(const float* __restrict__ inp,
                                            const float* __restrict__ outp,
                                            size_t off, int y, int x0, float2* dst) {
    if (y < 0 || y >= H) {
        #pragma unroll
        for (int j = 0; j < 8; j++) dst[j] = make_float2(0.0f, 0.0f);
    } else {
        const float4* pi = reinterpret_cast<const float4*>(inp  + off + (size_t)y * W + x0);
        const float4* po = reinterpret_cast<const float4*>(outp + off + (size_t)y * W + x0);
        float4 a = pi[0], b = pi[1];
        float4 c = po[0], d = po[1];
        dst[0] = make_float2(a.x, c.x); dst[1] = make_float2(a.y, c.y);
        dst[2] = make_float2(a.z, c.z); dst[3] = make_float2(a.w, c.w);
        dst[4] = make_float2(b.x, d.x); dst[5] = make_float2(b.y, d.y);
        dst[6] = make_float2(b.z, d.z); dst[7] = make_float2(b.w, d.w);
    }
}

__device__ __forceinline__ void load_mask_row(const float* __restrict__ mask, size_t off,
                                              int y, int x0, float* dst) {
    const float4* p = reinterpret_cast<const float4*>(mask + off + (size_t)y * W + x0);
    float4 a = p[0];
    float4 b = p[1];
    dst[0] = a.x; dst[1] = a.y; dst[2] = a.z; dst[3] = a.w;
    dst[4] = b.x; dst[5] = b.y; dst[6] = b.z; dst[7] = b.w;
}

// 1-wave blocks (64 threads): scheduling quantum = 1 wave (was 4), no
// __syncthreads / LDS in the hot kernel — retiring waves immediately free a
// slot, shrinking the straggler tail R5 measured (occupancy 16.7%, both pipes
// idle). Same BAND=2 rolling-window state -> stays in the <=128-VGPR /
// 16-waves-per-CU tier. No fused tail (R3/R4), no XCD swizzle (R5).
__global__ __launch_bounds__(64) void radiomics_main(
    const float* __restrict__ inp, const float* __restrict__ outp,
    const float* __restrict__ mask, double* __restrict__ partials)
{
    const int lane = threadIdx.x;                // 0..63, one wave per block
    const int gwave = blockIdx.x;                // 0..8191
    const int b = gwave >> 8;                    // gwave / (H/BAND = 256)
    const int band = gwave & 255;
    const int y0 = band * BAND;
    const size_t off = (size_t)b * H * W;
    const int x0 = lane * 8;

    // rolling 3-row packed window (x=inp, y=outp) + current mask row
    float2 P[8], C[8], N[8];
    float  Mk[8];

    load_row_pk(inp, outp, off, y0 - 1, x0, P);
    load_row_pk(inp, outp, off, y0,     x0, C);
    load_row_pk(inp, outp, off, y0 + 1, x0, N);
    load_mask_row(mask, off, y0, x0, Mk);

    float  acc0 = 0.0f, accT = 0.0f, accS = 0.0f;
    float2 am1 = make_float2(0,0), am2 = make_float2(0,0);
    float2 am3 = make_float2(0,0), am4 = make_float2(0,0);

    const float inv9 = 1.0f / 9.0f;

    #pragma unroll
    for (int i = 0; i < BAND; i++) {
        if (i) {
            #pragma unroll
            for (int j = 0; j < 8; j++) { P[j] = C[j]; C[j] = N[j]; }
            load_row_pk(inp, outp, off, y0 + i + 1, x0, N);
            load_mask_row(mask, off, y0 + i, x0, Mk);
        }

        // vertical column sums (packed: both images at once)
        float2 s1[8], s2[8];
        #pragma unroll
        for (int j = 0; j < 8; j++) {
            s1[j] = pk_add(pk_add(P[j], C[j]), N[j]);
            s2[j] = pk_fma(P[j], P[j], pk_fma(C[j], C[j], pk_mul(N[j], N[j])));
        }
        // horizontal halos via cross-lane shuffle; lane0/63 are true zero padding
        float2 h1l = shfl_up1_f2(s1[7], lane), h1r = shfl_dn1_f2(s1[0], lane);
        float2 h2l = shfl_up1_f2(s2[7], lane), h2r = shfl_dn1_f2(s2[0], lane);
        float2 hcl = shfl_up1_f2(C[7],  lane), hcr = shfl_dn1_f2(C[0],  lane);

        #pragma unroll
        for (int j = 0; j < 8; j++) {
            float2 l1 = (j == 0) ? h1l : s1[j-1];
            float2 r1 = (j == 7) ? h1r : s1[j+1];
            float2 l2 = (j == 0) ? h2l : s2[j-1];
            float2 r2 = (j == 7) ? h2r : s2[j+1];
            float2 mn = pk_muls(pk_add(pk_add(l1, s1[j]), r1), inv9);
            float2 e2 = pk_muls(pk_add(pk_add(l2, s2[j]), r2), inv9);
            float2 tv = pk_fma(make_float2(-mn.x, -mn.y), mn, e2);   // E[x^2]-E[x]^2
            float2 cl = (j == 0) ? hcl : C[j-1];
            float2 cr = (j == 7) ? hcr : C[j+1];
            // up+down+left+right-4c = (s1-C) + cl + cr - 4C
            float2 lp = pk_sub(pk_add(pk_add(pk_sub(s1[j], C[j]), cl), cr),
                               pk_muls(C[j], 4.0f));
            float m = Mk[j];
            accT += m * fabsf(tv.y - tv.x);     // m>=0: |a*m-b*m| == m*|a-b|
            accS += m * fabsf(lp.y - lp.x);
            acc0 += m;
            // raw masked moments, packed (x=inp, y=outp)
            float2 X = C[j];
            float2 t = pk_muls(X, m);
            am1 = pk_add(am1, t); t = pk_mul(t, X);
            am2 = pk_add(am2, t); t = pk_mul(t, X);
            am3 = pk_add(am3, t); t = pk_mul(t, X);
            am4 = pk_add(am4, t);
        }
    }

    // wave-level fp32 reduce; lane 0 writes the block's 11 fp64 partials.
    float acc[NQ] = { acc0, am1.x, am2.x, am3.x, am4.x,
                            am1.y, am2.y, am3.y, am4.y, accT, accS };
    #pragma unroll
    for (int q = 0; q < NQ; q++) {
        float v = acc[q];
        #pragma unroll
        for (int o = 32; o > 0; o >>= 1) v += __shfl_down(v, o);
        acc[q] = v;
    }
    if (lane == 0) {
        #pragma unroll
        for (int q = 0; q < NQ; q++)
            partials[(size_t)gwave * NQ + q] = (double)acc[q];
    }
}

__global__ __launch_bounds__(1024) void radiomics_final(
    const double* __restrict__ partials, int nblk, float* __restrict__ out4, double inv_n)
{
    const int tid = threadIdx.x;
    const int lane = tid & 63;
    const int w = tid >> 6;                      // 0..15
    double q[NQ];
    #pragma unroll
    for (int k = 0; k < NQ; k++) q[k] = 0.0;
    for (int i = tid; i < nblk; i += 1024) {
        #pragma unroll
        for (int k = 0; k < NQ; k++) q[k] += partials[(size_t)i * NQ + k];
    }
    #pragma unroll
    for (int k = 0; k < NQ; k++) {
        #pragma unroll
        for (int o = 32; o > 0; o >>= 1) q[k] += __shfl_down(q[k], o);
    }
    __shared__ double red[16][NQ];
    if (lane == 0) {
        #pragma unroll
        for (int k = 0; k < NQ; k++) red[w][k] = q[k];
    }
    __syncthreads();
    if (tid == 0) {
        double s[NQ];
        #pragma unroll
        for (int k = 0; k < NQ; k++) {
            double t = 0.0;
            #pragma unroll
            for (int r = 0; r < 16; r++) t += red[r][k];
            s[k] = t;
        }
        const double EPS = 1e-8;
        double S0 = s[0];
        double ms = S0 + EPS;
        double im = s[1] / ms, om = s[5] / ms;
        double im2 = im * im, im3 = im2 * im, im4 = im2 * im2;
        double om2 = om * om, om3 = om2 * om, om4 = om2 * om2;
        double di2 = s[2] - 2.0*im*s[1] + im2*S0;
        double do2 = s[6] - 2.0*om*s[5] + om2*S0;
        double iv = di2 / ms, ov = do2 / ms;
        double di3 = s[3] - 3.0*im*s[2] + 3.0*im2*s[1] - im3*S0;
        double do3 = s[7] - 3.0*om*s[6] + 3.0*om2*s[5] - om3*S0;
        double isk = di3 / (ms * (iv * sqrt(iv) + EPS));
        double osk = do3 / (ms * (ov * sqrt(ov) + EPS));
        double di4 = s[4] - 4.0*im*s[3] + 6.0*im2*s[2] - 4.0*im3*s[1] + im4*S0;
        double do4 = s[8] - 4.0*om*s[7] + 6.0*om2*s[6] - 4.0*om3*s[5] + om4*S0;
        double iku = di4 / (ms * (iv * iv + EPS));
        double oku = do4 / (ms * (ov * ov + EPS));
        double intensity = (im-om)*(im-om) + (iv-ov)*(iv-ov)
                         + (isk-osk)*(isk-osk) + (iku-oku)*(iku-oku);
        double texture = s[9]  * inv_n;
        double shape   = s[10] * inv_n;
        // TEXTURE_W=1.0, SHAPE_W=0.5, INTENSITY_W=1.0
        double total = intensity + texture + 0.5 * shape;
        out4[0] = (float)intensity;
        out4[1] = (float)texture;
        out4[2] = (float)shape;
        out4[3] = (float)total;
    }
}

extern "C" void kernel_launch(void* const* d_in, const int* in_sizes, int n_in,
                              void* d_out, int out_size, void* d_ws, size_t ws_size,
                              hipStream_t stream) {
    const float* inp  = (const float*)d_in[0];
    const float* outp = (const float*)d_in[1];
    const float* mask = (const float*)d_in[2];
    const int total = in_sizes[0];             // 32*1*512*512
    const int nimg  = total / (H * W);         // 32
    const int nblk  = nimg * (H / BAND);       // 8192 one-wave blocks
    double* partials = (double*)d_ws;          // nblk*NQ doubles, fully overwritten
    const double inv_n = 1.0 / (double)total;

    radiomics_main<<<nblk, 64, 0, stream>>>(inp, outp, mask, partials);
    radiomics_final<<<1, 1024, 0, stream>>>(partials, nblk, (float*)d_out, inv_n);
}

// Round 8
// 130.926 us; speedup vs baseline: 1.0485x; 1.0485x over previous
//
#include <hip/hip_runtime.h>
#include <math.h>

#define H 512
#define W 512
#define BAND 2
#define NQ 11   // 0:s0(mask) 1-4:s1i..s4i 5-8:s1o..s4o 9:tex 10:shape

__device__ __forceinline__ float2 shfl_up1_f2(float2 v, int lane, float2 edge) {
    float2 r;
    r.x = __shfl_up(v.x, 1);
    r.y = __shfl_up(v.y, 1);
    if (lane == 0) r = edge;       // wave-left halo (true border -> caller passes 0)
    return r;
}
__device__ __forceinline__ float2 shfl_dn1_f2(float2 v, int lane, float2 edge) {
    float2 r;
    r.x = __shfl_down(v.x, 1);
    r.y = __shfl_down(v.y, 1);
    if (lane == 63) r = edge;      // wave-right halo
    return r;
}

__device__ __forceinline__ float2 pk_add(float2 a, float2 b) { return make_float2(a.x + b.x, a.y + b.y); }
__device__ __forceinline__ float2 pk_sub(float2 a, float2 b) { return make_float2(a.x - b.x, a.y - b.y); }
__device__ __forceinline__ float2 pk_mul(float2 a, float2 b) { return make_float2(a.x * b.x, a.y * b.y); }
__device__ __forceinline__ float2 pk_muls(float2 a, float s) { return make_float2(a.x * s, a.y * s); }
__device__ __forceinline__ float2 pk_fma(float2 a, float2 b, float2 c) {
    return make_float2(fmaf(a.x, b.x, c.x), fmaf(a.y, b.y, c.y));
}

// One row, 4 px/lane, both images packed + the wave's two halo columns
// (uniform address across lanes -> broadcast load). Verified correct in R4.
__device__ __forceinline__ void load_row4(const float* __restrict__ inp,
                                          const float* __restrict__ outp,
                                          size_t off, int y, int x0,
                                          int xl, int xr, bool hasL, bool hasR,
                                          float2* dst, float2* lh, float2* rh) {
    if (y < 0 || y >= H) {
        #pragma unroll
        for (int j = 0; j < 4; j++) dst[j] = make_float2(0.0f, 0.0f);
        *lh = make_float2(0.0f, 0.0f);
        *rh = make_float2(0.0f, 0.0f);
    } else {
        const size_t rowo = off + (size_t)y * W;
        float4 a = *reinterpret_cast<const float4*>(inp  + rowo + x0);
        float4 c = *reinterpret_cast<const float4*>(outp + rowo + x0);
        dst[0] = make_float2(a.x, c.x); dst[1] = make_float2(a.y, c.y);
        dst[2] = make_float2(a.z, c.z); dst[3] = make_float2(a.w, c.w);
        *lh = hasL ? make_float2(inp[rowo + xl], outp[rowo + xl]) : make_float2(0.0f, 0.0f);
        *rh = hasR ? make_float2(inp[rowo + xr], outp[rowo + xr]) : make_float2(0.0f, 0.0f);
    }
}

__device__ __forceinline__ void load_mask_row4(const float* __restrict__ mask, size_t off,
                                               int y, int x0, float* dst) {
    float4 a = *reinterpret_cast<const float4*>(mask + off + (size_t)y * W + x0);
    dst[0] = a.x; dst[1] = a.y; dst[2] = a.z; dst[3] = a.w;
}

// 4 px/lane + x-split 2: per-wave row state halves vs 8 px/lane -> target
// 72-80 VGPR (R5 measured 104 at 8 px) = 6-7 waves/SIMD instead of 4.
// That is the only untested lever against R5's latency-bound profile
// (Occ 17%, VALU 25%, HBM 15%). Two kernels (R3/R4: fusion fences hurt),
// no XCD swizzle (R5: -3 us), 4-wave blocks (R7: 1-wave blocks hurt).
__global__ __launch_bounds__(256) void radiomics_main(
    const float* __restrict__ inp, const float* __restrict__ outp,
    const float* __restrict__ mask, double* __restrict__ partials)
{
    const int tid = threadIdx.x;
    const int lane = tid & 63;
    const int wib = tid >> 6;                    // wave in block (0..3)
    const int gwave = blockIdx.x * 4 + wib;      // 0..16383
    const int xh   = gwave & 1;                  // x half (0:[0,256) 1:[256,512))
    const int band = (gwave >> 1) & 255;         // 256 bands of 2 rows
    const int b    = gwave >> 9;                 // image 0..31
    const int y0 = band * BAND;
    const size_t off = (size_t)b * (H * W);
    const int xbase = xh << 8;
    const int x0 = xbase + lane * 4;
    const int xl = xbase - 1;                    // valid iff xh==1
    const int xr = xbase + 256;                  // valid iff xh==0
    const bool hasL = (xh == 1);
    const bool hasR = (xh == 0);

    // rolling 3-row packed window + per-row halo columns
    float2 P[4], C[4], N[4];
    float2 lhP, lhC, lhN, rhP, rhC, rhN;
    float  Mk[4];

    load_row4(inp, outp, off, y0 - 1, x0, xl, xr, hasL, hasR, P, &lhP, &rhP);
    load_row4(inp, outp, off, y0,     x0, xl, xr, hasL, hasR, C, &lhC, &rhC);
    load_row4(inp, outp, off, y0 + 1, x0, xl, xr, hasL, hasR, N, &lhN, &rhN);
    load_mask_row4(mask, off, y0, x0, Mk);

    float  acc0 = 0.0f, accT = 0.0f, accS = 0.0f;
    float2 am1 = make_float2(0,0), am2 = make_float2(0,0);
    float2 am3 = make_float2(0,0), am4 = make_float2(0,0);

    const float inv9 = 1.0f / 9.0f;

    #pragma unroll
    for (int i = 0; i < BAND; i++) {
        if (i) {
            #pragma unroll
            for (int j = 0; j < 4; j++) { P[j] = C[j]; C[j] = N[j]; }
            lhP = lhC; lhC = lhN; rhP = rhC; rhC = rhN;
            load_row4(inp, outp, off, y0 + i + 1, x0, xl, xr, hasL, hasR, N, &lhN, &rhN);
            load_mask_row4(mask, off, y0 + i, x0, Mk);
        }

        // vertical column sums (packed: both images at once)
        float2 s1[4], s2[4];
        #pragma unroll
        for (int j = 0; j < 4; j++) {
            s1[j] = pk_add(pk_add(P[j], C[j]), N[j]);
            s2[j] = pk_fma(P[j], P[j], pk_fma(C[j], C[j], pk_mul(N[j], N[j])));
        }
        // halo-column vertical sums (uniform across lanes)
        float2 es1l = pk_add(pk_add(lhP, lhC), lhN);
        float2 es2l = pk_fma(lhP, lhP, pk_fma(lhC, lhC, pk_mul(lhN, lhN)));
        float2 es1r = pk_add(pk_add(rhP, rhC), rhN);
        float2 es2r = pk_fma(rhP, rhP, pk_fma(rhC, rhC, pk_mul(rhN, rhN)));

        // horizontal halos via cross-lane shuffle; wave edges use halo columns
        float2 h1l = shfl_up1_f2(s1[3], lane, es1l), h1r = shfl_dn1_f2(s1[0], lane, es1r);
        float2 h2l = shfl_up1_f2(s2[3], lane, es2l), h2r = shfl_dn1_f2(s2[0], lane, es2r);
        float2 hcl = shfl_up1_f2(C[3],  lane, lhC),  hcr = shfl_dn1_f2(C[0],  lane, rhC);

        #pragma unroll
        for (int j = 0; j < 4; j++) {
            float2 l1 = (j == 0) ? h1l : s1[j-1];
            float2 r1 = (j == 3) ? h1r : s1[j+1];
            float2 l2 = (j == 0) ? h2l : s2[j-1];
            float2 r2 = (j == 3) ? h2r : s2[j+1];
            float2 mn = pk_muls(pk_add(pk_add(l1, s1[j]), r1), inv9);
            float2 e2 = pk_muls(pk_add(pk_add(l2, s2[j]), r2), inv9);
            float2 tv = pk_fma(make_float2(-mn.x, -mn.y), mn, e2);   // E[x^2]-E[x]^2
            float2 cl = (j == 0) ? hcl : C[j-1];
            float2 cr = (j == 3) ? hcr : C[j+1];
            // up+down+left+right-4c = (s1-C) + cl + cr - 4C
            float2 lp = pk_sub(pk_add(pk_add(pk_sub(s1[j], C[j]), cl), cr),
                               pk_muls(C[j], 4.0f));
            float m = Mk[j];
            accT += m * fabsf(tv.y - tv.x);     // m>=0: |a*m-b*m| == m*|a-b|
            accS += m * fabsf(lp.y - lp.x);
            acc0 += m;
            // raw masked moments, packed (x=inp, y=outp)
            float2 X = C[j];
            float2 t = pk_muls(X, m);
            am1 = pk_add(am1, t); t = pk_mul(t, X);
            am2 = pk_add(am2, t); t = pk_mul(t, X);
            am3 = pk_add(am3, t); t = pk_mul(t, X);
            am4 = pk_add(am4, t);
        }
    }

    // wave-level fp32 reduce, then fp64 per-block partial (no global atomics)
    float acc[NQ] = { acc0, am1.x, am2.x, am3.x, am4.x,
                            am1.y, am2.y, am3.y, am4.y, accT, accS };
    #pragma unroll
    for (int q = 0; q < NQ; q++) {
        float v = acc[q];
        #pragma unroll
        for (int o = 32; o > 0; o >>= 1) v += __shfl_down(v, o);
        acc[q] = v;
    }
    __shared__ double red[4][NQ];
    if (lane == 0) {
        #pragma unroll
        for (int q = 0; q < NQ; q++) red[wib][q] = (double)acc[q];
    }
    __syncthreads();
    if (tid < NQ) {
        double s = red[0][tid] + red[1][tid] + red[2][tid] + red[3][tid];
        partials[(size_t)blockIdx.x * NQ + tid] = s;
    }
}

__global__ __launch_bounds__(256) void radiomics_final(
    const double* __restrict__ partials, int nblk, float* __restrict__ out4, double inv_n)
{
    const int tid = threadIdx.x;
    const int lane = tid & 63;
    const int w = tid >> 6;
    double q[NQ];
    #pragma unroll
    for (int k = 0; k < NQ; k++) q[k] = 0.0;
    for (int i = tid; i < nblk; i += 256) {
        #pragma unroll
        for (int k = 0; k < NQ; k++) q[k] += partials[(size_t)i * NQ + k];
    }
    #pragma unroll
    for (int k = 0; k < NQ; k++) {
        #pragma unroll
        for (int o = 32; o > 0; o >>= 1) q[k] += __shfl_down(q[k], o);
    }
    __shared__ double red[4][NQ];
    if (lane == 0) {
        #pragma unroll
        for (int k = 0; k < NQ; k++) red[w][k] = q[k];
    }
    __syncthreads();
    if (tid == 0) {
        double s[NQ];
        #pragma unroll
        for (int k = 0; k < NQ; k++) s[k] = red[0][k] + red[1][k] + red[2][k] + red[3][k];
        const double EPS = 1e-8;
        double S0 = s[0];
        double ms = S0 + EPS;
        double im = s[1] / ms, om = s[5] / ms;
        double im2 = im * im, im3 = im2 * im, im4 = im2 * im2;
        double om2 = om * om, om3 = om2 * om, om4 = om2 * om2;
        double di2 = s[2] - 2.0*im*s[1] + im2*S0;
        double do2 = s[6] - 2.0*om*s[5] + om2*S0;
        double iv = di2 / ms, ov = do2 / ms;
        double di3 = s[3] - 3.0*im*s[2] + 3.0*im2*s[1] - im3*S0;
        double do3 = s[7] - 3.0*om*s[6] + 3.0*om2*s[5] - om3*S0;
        double isk = di3 / (ms * (iv * sqrt(iv) + EPS));
        double osk = do3 / (ms * (ov * sqrt(ov) + EPS));
        double di4 = s[4] - 4.0*im*s[3] + 6.0*im2*s[2] - 4.0*im3*s[1] + im4*S0;
        double do4 = s[8] - 4.0*om*s[7] + 6.0*om2*s[6] - 4.0*om3*s[5] + om4*S0;
        double iku = di4 / (ms * (iv * iv + EPS));
        double oku = do4 / (ms * (ov * ov + EPS));
        double intensity = (im-om)*(im-om) + (iv-ov)*(iv-ov)
                         + (isk-osk)*(isk-osk) + (iku-oku)*(iku-oku);
        double texture = s[9]  * inv_n;
        double shape   = s[10] * inv_n;
        // TEXTURE_W=1.0, SHAPE_W=0.5, INTENSITY_W=1.0
        double total = intensity + texture + 0.5 * shape;
        out4[0] = (float)intensity;
        out4[1] = (float)texture;
        out4[2] = (float)shape;
        out4[3] = (float)total;
    }
}

extern "C" void kernel_launch(void* const* d_in, const int* in_sizes, int n_in,
                              void* d_out, int out_size, void* d_ws, size_t ws_size,
                              hipStream_t stream) {
    const float* inp  = (const float*)d_in[0];
    const float* outp = (const float*)d_in[1];
    const float* mask = (const float*)d_in[2];
    const int total = in_sizes[0];             // 32*1*512*512
    const int nimg  = total / (H * W);         // 32
    const int nwaves = nimg * (H / BAND) * 2;  // 16384 (x-split by 2)
    const int nblk   = nwaves / 4;             // 4096 blocks of 256 threads
    double* partials = (double*)d_ws;          // nblk*NQ doubles, fully overwritten
    const double inv_n = 1.0 / (double)total;

    radiomics_main<<<nblk, 256, 0, stream>>>(inp, outp, mask, partials);
    radiomics_final<<<1, 256, 0, stream>>>(partials, nblk, (float*)d_out, inv_n);
}

// Round 9
// 123.866 us; speedup vs baseline: 1.1082x; 1.0570x over previous
//
#include <hip/hip_runtime.h>
#include <math.h>

#define H 512
#define W 512
#define BAND 4
#define NQ 11   // 0:s0(mask) 1-4:s1i..s4i 5-8:s1o..s4o 9:tex 10:shape

__device__ __forceinline__ float2 shfl_up1_f2(float2 v, int lane) {
    float2 r;
    r.x = __shfl_up(v.x, 1);
    r.y = __shfl_up(v.y, 1);
    if (lane == 0) { r.x = 0.0f; r.y = 0.0f; }
    return r;
}
__device__ __forceinline__ float2 shfl_dn1_f2(float2 v, int lane) {
    float2 r;
    r.x = __shfl_down(v.x, 1);
    r.y = __shfl_down(v.y, 1);
    if (lane == 63) { r.x = 0.0f; r.y = 0.0f; }
    return r;
}

__device__ __forceinline__ float2 pk_add(float2 a, float2 b) { return make_float2(a.x + b.x, a.y + b.y); }
__device__ __forceinline__ float2 pk_sub(float2 a, float2 b) { return make_float2(a.x - b.x, a.y - b.y); }
__device__ __forceinline__ float2 pk_mul(float2 a, float2 b) { return make_float2(a.x * b.x, a.y * b.y); }
__device__ __forceinline__ float2 pk_muls(float2 a, float s) { return make_float2(a.x * s, a.y * s); }
__device__ __forceinline__ float2 pk_fma(float2 a, float2 b, float2 c) {
    return make_float2(fmaf(a.x, b.x, c.x), fmaf(a.y, b.y, c.y));
}

// load one row of BOTH images, interleaved: dst[j] = (inp[y][x0+j], outp[y][x0+j])
__device__ __forceinline__ void load_row_pk(const float* __restrict__ inp,
                                            const float* __restrict__ outp,
                                            size_t off, int y, int x0, float2* dst) {
    if (y < 0 || y >= H) {
        #pragma unroll
        for (int j = 0; j < 8; j++) dst[j] = make_float2(0.0f, 0.0f);
    } else {
        const float4* pi = reinterpret_cast<const float4*>(inp  + off + (size_t)y * W + x0);
        const float4* po = reinterpret_cast<const float4*>(outp + off + (size_t)y * W + x0);
        float4 a = pi[0], b = pi[1];
        float4 c = po[0], d = po[1];
        dst[0] = make_float2(a.x, c.x); dst[1] = make_float2(a.y, c.y);
        dst[2] = make_float2(a.z, c.z); dst[3] = make_float2(a.w, c.w);
        dst[4] = make_float2(b.x, d.x); dst[5] = make_float2(b.y, d.y);
        dst[6] = make_float2(b.z, d.z); dst[7] = make_float2(b.w, d.w);
    }
}

__device__ __forceinline__ void load_mask_row(const float* __restrict__ mask, size_t off,
                                              int y, int x0, float* dst) {
    const float4* p = reinterpret_cast<const float4*>(mask + off + (size_t)y * W + x0);
    float4 a = p[0];
    float4 b = p[1];
    dst[0] = a.x; dst[1] = a.y; dst[2] = a.z; dst[3] = a.w;
    dst[4] = b.x; dst[5] = b.y; dst[6] = b.z; dst[7] = b.w;
}

// Best-measured structure (R0 = 124.1 us; this session's ladder):
//   BAND=4, 8 px/lane, two kernels, plain blockIdx order.
// Levers tested and rejected: coop-launch fusion (graph-capture fail, R1),
// ticket fusion (fence cost + VGPR tier collapse, R3/R4), XCD swizzle
// (-3us, R5), BAND=2 oversubscription (neutral, R6), 1-wave blocks
// (-12us, R7), 4px/lane x-split (-6us, R8). Only retained delta vs R0:
// m*|a-b| fold (verified absmax 0 in R6).
__global__ __launch_bounds__(256) void radiomics_main(
    const float* __restrict__ inp, const float* __restrict__ outp,
    const float* __restrict__ mask, double* __restrict__ partials)
{
    const int tid = threadIdx.x;
    const int lane = tid & 63;
    const int wib = tid >> 6;                    // wave in block (0..3)
    const int gwave = blockIdx.x * 4 + wib;
    const int b = gwave >> 7;                    // gwave / (H/BAND = 128)
    const int band = gwave & 127;
    const int y0 = band * BAND;
    const size_t off = (size_t)b * H * W;
    const int x0 = lane * 8;

    // rolling 3-row packed window (x=inp, y=outp) + current mask row
    float2 P[8], C[8], N[8];
    float  Mk[8];

    load_row_pk(inp, outp, off, y0 - 1, x0, P);
    load_row_pk(inp, outp, off, y0,     x0, C);
    load_row_pk(inp, outp, off, y0 + 1, x0, N);
    load_mask_row(mask, off, y0, x0, Mk);

    float  acc0 = 0.0f, accT = 0.0f, accS = 0.0f;
    float2 am1 = make_float2(0,0), am2 = make_float2(0,0);
    float2 am3 = make_float2(0,0), am4 = make_float2(0,0);

    const float inv9 = 1.0f / 9.0f;

    #pragma unroll
    for (int i = 0; i < BAND; i++) {
        if (i) {
            #pragma unroll
            for (int j = 0; j < 8; j++) { P[j] = C[j]; C[j] = N[j]; }
            load_row_pk(inp, outp, off, y0 + i + 1, x0, N);
            load_mask_row(mask, off, y0 + i, x0, Mk);
        }

        // vertical column sums (packed: both images at once)
        float2 s1[8], s2[8];
        #pragma unroll
        for (int j = 0; j < 8; j++) {
            s1[j] = pk_add(pk_add(P[j], C[j]), N[j]);
            s2[j] = pk_fma(P[j], P[j], pk_fma(C[j], C[j], pk_mul(N[j], N[j])));
        }
        // horizontal halos via cross-lane shuffle; lane0/63 are true zero padding
        float2 h1l = shfl_up1_f2(s1[7], lane), h1r = shfl_dn1_f2(s1[0], lane);
        float2 h2l = shfl_up1_f2(s2[7], lane), h2r = shfl_dn1_f2(s2[0], lane);
        float2 hcl = shfl_up1_f2(C[7],  lane), hcr = shfl_dn1_f2(C[0],  lane);

        #pragma unroll
        for (int j = 0; j < 8; j++) {
            float2 l1 = (j == 0) ? h1l : s1[j-1];
            float2 r1 = (j == 7) ? h1r : s1[j+1];
            float2 l2 = (j == 0) ? h2l : s2[j-1];
            float2 r2 = (j == 7) ? h2r : s2[j+1];
            float2 mn = pk_muls(pk_add(pk_add(l1, s1[j]), r1), inv9);
            float2 e2 = pk_muls(pk_add(pk_add(l2, s2[j]), r2), inv9);
            float2 tv = pk_fma(make_float2(-mn.x, -mn.y), mn, e2);   // E[x^2]-E[x]^2
            float2 cl = (j == 0) ? hcl : C[j-1];
            float2 cr = (j == 7) ? hcr : C[j+1];
            // up+down+left+right-4c = (s1-C) + cl + cr - 4C
            float2 lp = pk_sub(pk_add(pk_add(pk_sub(s1[j], C[j]), cl), cr),
                               pk_muls(C[j], 4.0f));
            float m = Mk[j];
            accT += m * fabsf(tv.y - tv.x);     // m>=0: |a*m-b*m| == m*|a-b|
            accS += m * fabsf(lp.y - lp.x);
            acc0 += m;
            // raw masked moments, packed (x=inp, y=outp)
            float2 X = C[j];
            float2 t = pk_muls(X, m);
            am1 = pk_add(am1, t); t = pk_mul(t, X);
            am2 = pk_add(am2, t); t = pk_mul(t, X);
            am3 = pk_add(am3, t); t = pk_mul(t, X);
            am4 = pk_add(am4, t);
        }
    }

    // wave-level fp32 reduce, then fp64 per-block partial (no global atomics)
    float acc[NQ] = { acc0, am1.x, am2.x, am3.x, am4.x,
                            am1.y, am2.y, am3.y, am4.y, accT, accS };
    #pragma unroll
    for (int q = 0; q < NQ; q++) {
        float v = acc[q];
        #pragma unroll
        for (int o = 32; o > 0; o >>= 1) v += __shfl_down(v, o);
        acc[q] = v;
    }
    __shared__ double red[4][NQ];
    if (lane == 0) {
        #pragma unroll
        for (int q = 0; q < NQ; q++) red[wib][q] = (double)acc[q];
    }
    __syncthreads();
    if (tid < NQ) {
        double s = red[0][tid] + red[1][tid] + red[2][tid] + red[3][tid];
        partials[(size_t)blockIdx.x * NQ + tid] = s;
    }
}

__global__ __launch_bounds__(256) void radiomics_final(
    const double* __restrict__ partials, int nblk, float* __restrict__ out4, double inv_n)
{
    const int tid = threadIdx.x;
    const int lane = tid & 63;
    const int w = tid >> 6;
    double q[NQ];
    #pragma unroll
    for (int k = 0; k < NQ; k++) q[k] = 0.0;
    for (int i = tid; i < nblk; i += 256) {
        #pragma unroll
        for (int k = 0; k < NQ; k++) q[k] += partials[(size_t)i * NQ + k];
    }
    #pragma unroll
    for (int k = 0; k < NQ; k++) {
        #pragma unroll
        for (int o = 32; o > 0; o >>= 1) q[k] += __shfl_down(q[k], o);
    }
    __shared__ double red[4][NQ];
    if (lane == 0) {
        #pragma unroll
        for (int k = 0; k < NQ; k++) red[w][k] = q[k];
    }
    __syncthreads();
    if (tid == 0) {
        double s[NQ];
        #pragma unroll
        for (int k = 0; k < NQ; k++) s[k] = red[0][k] + red[1][k] + red[2][k] + red[3][k];
        const double EPS = 1e-8;
        double S0 = s[0];
        double ms = S0 + EPS;
        double im = s[1] / ms, om = s[5] / ms;
        double im2 = im * im, im3 = im2 * im, im4 = im2 * im2;
        double om2 = om * om, om3 = om2 * om, om4 = om2 * om2;
        double di2 = s[2] - 2.0*im*s[1] + im2*S0;
        double do2 = s[6] - 2.0*om*s[5] + om2*S0;
        double iv = di2 / ms, ov = do2 / ms;
        double di3 = s[3] - 3.0*im*s[2] + 3.0*im2*s[1] - im3*S0;
        double do3 = s[7] - 3.0*om*s[6] + 3.0*om2*s[5] - om3*S0;
        double isk = di3 / (ms * (iv * sqrt(iv) + EPS));
        double osk = do3 / (ms * (ov * sqrt(ov) + EPS));
        double di4 = s[4] - 4.0*im*s[3] + 6.0*im2*s[2] - 4.0*im3*s[1] + im4*S0;
        double do4 = s[8] - 4.0*om*s[7] + 6.0*om2*s[6] - 4.0*om3*s[5] + om4*S0;
        double iku = di4 / (ms * (iv * iv + EPS));
        double oku = do4 / (ms * (ov * ov + EPS));
        double intensity = (im-om)*(im-om) + (iv-ov)*(iv-ov)
                         + (isk-osk)*(isk-osk) + (iku-oku)*(iku-oku);
        double texture = s[9]  * inv_n;
        double shape   = s[10] * inv_n;
        // TEXTURE_W=1.0, SHAPE_W=0.5, INTENSITY_W=1.0
        double total = intensity + texture + 0.5 * shape;
        out4[0] = (float)intensity;
        out4[1] = (float)texture;
        out4[2] = (float)shape;
        out4[3] = (float)total;
    }
}

extern "C" void kernel_launch(void* const* d_in, const int* in_sizes, int n_in,
                              void* d_out, int out_size, void* d_ws, size_t ws_size,
                              hipStream_t stream) {
    const float* inp  = (const float*)d_in[0];
    const float* outp = (const float*)d_in[1];
    const float* mask = (const float*)d_in[2];
    const int total = in_sizes[0];             // 32*1*512*512
    const int nimg  = total / (H * W);         // 32
    const int nwaves = nimg * (H / BAND);      // 4096
    const int nblk   = nwaves / 4;             // 1024 blocks of 256 threads
    double* partials = (double*)d_ws;          // nblk*NQ doubles, fully overwritten
    const double inv_n = 1.0 / (double)total;

    radiomics_main<<<nblk, 256, 0, stream>>>(inp, outp, mask, partials);
    radiomics_final<<<1, 256, 0, stream>>>(partials, nblk, (float*)d_out, inv_n);
}